// Round 4
// baseline (560.652 us; speedup 1.0000x reference)
//
#include <hip/hip_runtime.h>
#include <cstdint>
#include <cstddef>

// ---------------------------------------------------------------------------
// SRPLayer: out = Psi_c @ x.T @ x, Psi_c = Psi - rowmean(Psi)
//   x [4096][8192] f32, Psi [2048][8192] f32, out [2048][8192] f32
// bf16 MFMA GEMMs, 8-phase-style schedule (T2 swizzle + counted vmcnt + T5).
// GEMM1: BM=128 fat-2-phase (16 MFMA/phase, B-frags held in regs).
// GEMM2: BM=256 4-phase, bF0 held (no re-read), phase3 barrier-free.
// ws: xb [D][N] bf16 @0 (64MB) | xtb [N][D] bf16 @64MB | pc [O][N] bf16 @128MB
//     | tmpb [O][D] bf16 @160MB
// ---------------------------------------------------------------------------

typedef __bf16 bf16x8 __attribute__((ext_vector_type(8)));
typedef float f32x4 __attribute__((ext_vector_type(4)));

__device__ __forceinline__ unsigned short f2bf(float f) {
  unsigned u = __builtin_bit_cast(unsigned, f);
  u += 0x7FFFu + ((u >> 16) & 1u);
  return (unsigned short)(u >> 16);
}

__device__ __forceinline__ void gload_lds16(const void* g, void* l) {
  // async global->LDS, 16B/lane; LDS dest must be wave-uniform base + lane*16
  __builtin_amdgcn_global_load_lds(
      (const __attribute__((address_space(1))) unsigned int*)g,
      (__attribute__((address_space(3))) unsigned int*)l, 16, 0, 0);
}

__device__ __forceinline__ void barrier_nofence() {
  asm volatile("" ::: "memory");
  __builtin_amdgcn_s_barrier();
  asm volatile("" ::: "memory");
}
#define WAIT_LGKM0()                                   \
  do {                                                 \
    asm volatile("s_waitcnt lgkmcnt(0)" ::: "memory"); \
    __builtin_amdgcn_sched_barrier(0);                 \
  } while (0)
#define WAITV(N) asm volatile("s_waitcnt vmcnt(" #N ")" ::: "memory")

// =================== GEMM1: C[M][Nc] = A[M][K] * B[Nc][K]^T =================
// BM=128, BN=256, BK=64; 8 waves 2Mx4N (per-wave 64x64... acc[4][4]).
// 2 fat phases per K-tile: p0 = mh0 x all-N (16 MFMA), p1 = mh1 x all-N.
// All stages target the inactive double-buffer half => strictly race-free.
__global__ __launch_bounds__(512, 2) void gemm2p(
    const unsigned short* __restrict__ A, const unsigned short* __restrict__ B,
    unsigned short* __restrict__ C, int M, int Nc, int K) {
  constexpr int BM = 128, BN = 256;
  constexpr int APLANE = BM * 64, ABUF = 2 * APLANE;   // 8KB plane, 16KB buf
  constexpr int BPLANE = BN * 64, BBUF = 2 * BPLANE;   // 16KB plane, 32KB buf
  __shared__ __align__(1024) char lds[2 * ABUF + 2 * BBUF];  // 96 KB
  char* Al = lds;
  char* Bl = lds + 2 * ABUF;

  const int nwg = gridDim.x * gridDim.y;
  const int wgid = blockIdx.y * gridDim.x + blockIdx.x;
  const int swz = (wgid & 7) * (nwg >> 3) + (wgid >> 3);  // nwg % 8 == 0
  const int bx = swz % gridDim.x, by = swz / gridDim.x;
  const int tileM = by * BM, tileN = bx * BN;

  const int t = threadIdx.x, lane = t & 63, wave = t >> 6;
  const int wm = wave >> 2, wn = wave & 3;
  const int rsel = lane & 15;
  const int cs = (((lane >> 4) ^ (((lane >> 3) & 1) << 1)) << 4);

  const unsigned short* Ag = A + (size_t)tileM * K;
  const unsigned short* Bg = B + (size_t)tileN * K;
  const int cgA = (((t & 3) ^ (((t >> 5) & 1) << 1))) * 8;
  const int NT = K / 64;

  auto stageA = [&](int h, int kt) {  // 1 gload: 64 rows incl both kk planes
    int b2 = kt & 1;
    int r = h * 64 + ((t >> 2) & 63);
    int kk = t >> 8;
    gload_lds16(Ag + (size_t)r * K + kt * 64 + kk * 32 + cgA,
                Al + b2 * ABUF + kk * APLANE + h * 4096 + (t & 255) * 16);
  };
  auto stageB = [&](int h, int kt) {  // 2 gloads: 128 rows x both planes
    int b2 = kt & 1;
#pragma unroll
    for (int kk = 0; kk < 2; ++kk) {
      int r = h * 128 + (t >> 2);
      gload_lds16(Bg + (size_t)r * K + kt * 64 + kk * 32 + cgA,
                  Bl + b2 * BBUF + kk * BPLANE + h * 8192 + t * 16);
    }
  };

  f32x4 acc[4][4] = {};
  bf16x8 aF[2][2], bFall[4][2];

  // prologue: tile0 fully staged; leave A1 in flight (drained at p0-end)
  stageB(0, 0); stageA(0, 0); stageB(1, 0); stageA(1, 0);
  WAITV(1);
  barrier_nofence();

  for (int kt = 0; kt < NT; ++kt) {
    const char* Ab = Al + (kt & 1) * ABUF;
    const char* Bb = Bl + (kt & 1) * BBUF;
    // ---- phase 0: read A-mh0 + ALL B; stage (kt+1).{B0,A0}; 16 MFMA
#pragma unroll
    for (int f = 0; f < 2; ++f)
#pragma unroll
      for (int kk = 0; kk < 2; ++kk)
        aF[f][kk] = *(const bf16x8*)(Ab + kk * APLANE +
                                     ((2 * f + wm) * 16 + rsel) * 64 + cs);
#pragma unroll
    for (int g = 0; g < 4; ++g)
#pragma unroll
      for (int kk = 0; kk < 2; ++kk)
        bFall[g][kk] = *(const bf16x8*)(Bb + kk * BPLANE +
                                        ((4 * g + wn) * 16 + rsel) * 64 + cs);
    if (kt + 1 < NT) { stageB(0, kt + 1); stageA(0, kt + 1); }
    barrier_nofence();
    WAIT_LGKM0();
    __builtin_amdgcn_s_setprio(1);
#pragma unroll
    for (int f = 0; f < 2; ++f)
#pragma unroll
      for (int g = 0; g < 4; ++g)
#pragma unroll
        for (int kk = 0; kk < 2; ++kk)
          acc[f][g] = __builtin_amdgcn_mfma_f32_16x16x32_bf16(
              aF[f][kk], bFall[g][kk], acc[f][g], 0, 0, 0);
    __builtin_amdgcn_s_setprio(0);
    if (kt == NT - 1) { WAITV(0); } else { WAITV(3); }  // drain (kt).A1
    barrier_nofence();
    // ---- phase 1: read A-mh1; stage (kt+1).{B1,A1}; 16 MFMA (bFall held)
#pragma unroll
    for (int f = 0; f < 2; ++f)
#pragma unroll
      for (int kk = 0; kk < 2; ++kk)
        aF[f][kk] = *(const bf16x8*)(Ab + kk * APLANE +
                                     ((2 * (f + 2) + wm) * 16 + rsel) * 64 + cs);
    if (kt + 1 < NT) { stageB(1, kt + 1); stageA(1, kt + 1); }
    barrier_nofence();
    WAIT_LGKM0();
    __builtin_amdgcn_s_setprio(1);
#pragma unroll
    for (int f = 0; f < 2; ++f)
#pragma unroll
      for (int g = 0; g < 4; ++g)
#pragma unroll
        for (int kk = 0; kk < 2; ++kk)
          acc[2 + f][g] = __builtin_amdgcn_mfma_f32_16x16x32_bf16(
              aF[f][kk], bFall[g][kk], acc[2 + f][g], 0, 0, 0);
    __builtin_amdgcn_s_setprio(0);
    WAITV(1);  // drain (kt+1).{B0,A0,B1}; leave (kt+1).A1
    barrier_nofence();
  }

#pragma unroll
  for (int f = 0; f < 4; ++f) {
    int row0 = tileM + (2 * f + wm) * 16 + ((lane >> 4) << 2);
#pragma unroll
    for (int g = 0; g < 4; ++g) {
      int col = tileN + (4 * g + wn) * 16 + rsel;
#pragma unroll
      for (int r = 0; r < 4; ++r)
        C[(size_t)(row0 + r) * Nc + col] = f2bf(acc[f][g][r]);
    }
  }
}

// =================== GEMM2: C[M][Nc] = A[M][K] * B[Nc][K]^T =================
// BM=256, BN=256, BK=64; 4 phases; bF0 held across tile (no nh0 re-read);
// phase 3 is barrier-free pure-MFMA + stage + counted vmcnt.
__global__ __launch_bounds__(512, 2) void gemm4p(
    const unsigned short* __restrict__ A, const unsigned short* __restrict__ B,
    float* __restrict__ C, int M, int Nc, int K) {
  constexpr int BM = 256, BN = 256;
  constexpr int APLANE = BM * 64, ABUF = 2 * APLANE;
  constexpr int BPLANE = BN * 64, BBUF = 2 * BPLANE;
  __shared__ __align__(1024) char lds[2 * ABUF + 2 * BBUF];  // 128 KB
  char* Al = lds;
  char* Bl = lds + 2 * ABUF;

  const int nwg = gridDim.x * gridDim.y;
  const int wgid = blockIdx.y * gridDim.x + blockIdx.x;
  const int swz = (wgid & 7) * (nwg >> 3) + (wgid >> 3);
  const int bx = swz % gridDim.x, by = swz / gridDim.x;
  const int tileM = by * BM, tileN = bx * BN;

  const int t = threadIdx.x, lane = t & 63, wave = t >> 6;
  const int wm = wave >> 2, wn = wave & 3;
  const int rsel = lane & 15;
  const int cs = (((lane >> 4) ^ (((lane >> 3) & 1) << 1)) << 4);

  const unsigned short* Ag = A + (size_t)tileM * K;
  const unsigned short* Bg = B + (size_t)tileN * K;
  const int cgA = (((t & 3) ^ (((t >> 5) & 1) << 1))) * 8;
  const int NT = K / 64;

  auto stageA = [&](int h, int kt) {
    int b2 = kt & 1;
#pragma unroll
    for (int kk = 0; kk < 2; ++kk) {
      int r = h * 128 + (t >> 2);
      gload_lds16(Ag + (size_t)r * K + kt * 64 + kk * 32 + cgA,
                  Al + b2 * ABUF + kk * APLANE + h * 8192 + t * 16);
    }
  };
  auto stageB = [&](int h, int kt) {
    int b2 = kt & 1;
#pragma unroll
    for (int kk = 0; kk < 2; ++kk) {
      int r = h * 128 + (t >> 2);
      gload_lds16(Bg + (size_t)r * K + kt * 64 + kk * 32 + cgA,
                  Bl + b2 * BBUF + kk * BPLANE + h * 8192 + t * 16);
    }
  };

  f32x4 acc[8][4] = {};
  bf16x8 aF[4][2], bF0[2][2], bF1[2][2];

  // prologue: tile0 fully + tile1.{A0,B1,A1}; tile0 guaranteed landed
  stageA(0, 0); stageB(1, 0); stageA(1, 0); stageB(0, 0);
  stageA(0, 1); stageB(1, 1); stageA(1, 1);
  WAITV(6);
  barrier_nofence();

  for (int kt = 0; kt < NT; ++kt) {
    const char* Ab = Al + (kt & 1) * ABUF;
    const char* Bb = Bl + (kt & 1) * BBUF;
    // ---- p0: read A-mh0 + B-nh0(bF0); stage (kt+1).B0; MFMA (0,0)
#pragma unroll
    for (int f = 0; f < 4; ++f)
#pragma unroll
      for (int kk = 0; kk < 2; ++kk)
        aF[f][kk] = *(const bf16x8*)(Ab + kk * APLANE +
                                     ((2 * f + wm) * 16 + rsel) * 64 + cs);
#pragma unroll
    for (int g = 0; g < 2; ++g)
#pragma unroll
      for (int kk = 0; kk < 2; ++kk)
        bF0[g][kk] = *(const bf16x8*)(Bb + kk * BPLANE +
                                      ((4 * g + wn) * 16 + rsel) * 64 + cs);
    if (kt + 1 < NT) stageB(0, kt + 1);
    barrier_nofence();
    WAIT_LGKM0();
    __builtin_amdgcn_s_setprio(1);
#pragma unroll
    for (int f = 0; f < 4; ++f)
#pragma unroll
      for (int g = 0; g < 2; ++g)
#pragma unroll
        for (int kk = 0; kk < 2; ++kk)
          acc[f][g] = __builtin_amdgcn_mfma_f32_16x16x32_bf16(
              aF[f][kk], bF0[g][kk], acc[f][g], 0, 0, 0);
    __builtin_amdgcn_s_setprio(0);
    barrier_nofence();
    // ---- p1: read B-nh1(bF1); stage (kt+2).A0; MFMA (0,1)
#pragma unroll
    for (int g = 0; g < 2; ++g)
#pragma unroll
      for (int kk = 0; kk < 2; ++kk)
        bF1[g][kk] = *(const bf16x8*)(Bb + kk * BPLANE +
                                      ((4 * (g + 2) + wn) * 16 + rsel) * 64 + cs);
    if (kt + 2 < NT) stageA(0, kt + 2);
    barrier_nofence();
    WAIT_LGKM0();
    __builtin_amdgcn_s_setprio(1);
#pragma unroll
    for (int f = 0; f < 4; ++f)
#pragma unroll
      for (int g = 0; g < 2; ++g)
#pragma unroll
        for (int kk = 0; kk < 2; ++kk)
          acc[f][2 + g] = __builtin_amdgcn_mfma_f32_16x16x32_bf16(
              aF[f][kk], bF1[g][kk], acc[f][2 + g], 0, 0, 0);
    __builtin_amdgcn_s_setprio(0);
    barrier_nofence();
    // ---- p2: read A-mh1; stage (kt+2).B1; MFMA (1,1)
#pragma unroll
    for (int f = 0; f < 4; ++f)
#pragma unroll
      for (int kk = 0; kk < 2; ++kk)
        aF[f][kk] = *(const bf16x8*)(Ab + kk * APLANE +
                                     ((2 * (f + 4) + wm) * 16 + rsel) * 64 + cs);
    if (kt + 2 < NT) stageB(1, kt + 2);
    barrier_nofence();
    WAIT_LGKM0();
    __builtin_amdgcn_s_setprio(1);
#pragma unroll
    for (int f = 0; f < 4; ++f)
#pragma unroll
      for (int g = 0; g < 2; ++g)
#pragma unroll
        for (int kk = 0; kk < 2; ++kk)
          acc[4 + f][2 + g] = __builtin_amdgcn_mfma_f32_16x16x32_bf16(
              aF[f][kk], bF1[g][kk], acc[4 + f][2 + g], 0, 0, 0);
    __builtin_amdgcn_s_setprio(0);
    barrier_nofence();
    // ---- p3: barrier-free; stage (kt+2).A1; MFMA (1,0) with held bF0
    if (kt + 2 < NT) stageA(1, kt + 2);
    __builtin_amdgcn_s_setprio(1);
#pragma unroll
    for (int f = 0; f < 4; ++f)
#pragma unroll
      for (int g = 0; g < 2; ++g)
#pragma unroll
        for (int kk = 0; kk < 2; ++kk)
          acc[4 + f][g] = __builtin_amdgcn_mfma_f32_16x16x32_bf16(
              aF[f][kk], bF0[g][kk], acc[4 + f][g], 0, 0, 0);
    __builtin_amdgcn_s_setprio(0);
    if (kt + 2 < NT) { WAITV(6); } else { WAITV(0); }
    barrier_nofence();
  }

#pragma unroll
  for (int f = 0; f < 8; ++f) {
    int row0 = tileM + (2 * f + wm) * 16 + ((lane >> 4) << 2);
#pragma unroll
    for (int g = 0; g < 4; ++g) {
      int col = tileN + (4 * g + wn) * 16 + rsel;
#pragma unroll
      for (int r = 0; r < 4; ++r)
        C[(size_t)(row0 + r) * Nc + col] = acc[f][g][r];
    }
  }
}

// ====== fused preprocessing: x -> {xb, xtb}; Psi -> centered bf16 pc ========
// blocks [0, 8192): 64x64 transpose/convert tiles; [8192, 10240): Psi rows.
__global__ void pre_kernel(const float* __restrict__ x,
                           const float* __restrict__ Psi,
                           unsigned short* __restrict__ xb,
                           unsigned short* __restrict__ xtb,
                           unsigned short* __restrict__ pc, int D, int N) {
  __shared__ unsigned short tileT[64][66];  // pad 66: <=4-way banks both sides
  __shared__ float red[4];
  const int bid = blockIdx.x, t = threadIdx.x;
  if (bid < 8192) {
    const int n0 = (bid & 127) * 64, d0 = (bid >> 7) * 64;
    const int tx = t & 15, ty = t >> 4;  // 16 x 16
#pragma unroll
    for (int dy = 0; dy < 4; ++dy) {
      int d = ty + 16 * dy;
      float4 v = *(const float4*)(x + (size_t)(d0 + d) * N + n0 + tx * 4);
      ushort4 o;
      o.x = f2bf(v.x); o.y = f2bf(v.y); o.z = f2bf(v.z); o.w = f2bf(v.w);
      *(ushort4*)(xb + (size_t)(d0 + d) * N + n0 + tx * 4) = o;
      tileT[tx * 4 + 0][d] = o.x;
      tileT[tx * 4 + 1][d] = o.y;
      tileT[tx * 4 + 2][d] = o.z;
      tileT[tx * 4 + 3][d] = o.w;
    }
    __syncthreads();
#pragma unroll
    for (int ny = 0; ny < 4; ++ny) {
      int n = ty + 16 * ny;
      ushort2 a = *(const ushort2*)&tileT[n][tx * 4];
      ushort2 b = *(const ushort2*)&tileT[n][tx * 4 + 2];
      ushort4 o; o.x = a.x; o.y = a.y; o.z = b.x; o.w = b.y;
      *(ushort4*)(xtb + (size_t)(n0 + n) * D + d0 + tx * 4) = o;
    }
  } else {
    const int row = bid - 8192;
    const float4* src = (const float4*)(Psi + (size_t)row * N);
    int n4 = N >> 2;
    float s = 0.f;
    for (int i = t; i < n4; i += blockDim.x) {
      float4 v = src[i];
      s += (v.x + v.y) + (v.z + v.w);
    }
#pragma unroll
    for (int off = 32; off > 0; off >>= 1) s += __shfl_down(s, off);
    if ((t & 63) == 0) red[t >> 6] = s;
    __syncthreads();
    float mean = (red[0] + red[1] + red[2] + red[3]) / (float)N;
    ushort4* dst = (ushort4*)(pc + (size_t)row * N);
    for (int i = t; i < n4; i += blockDim.x) {
      float4 v = src[i];
      ushort4 o;
      o.x = f2bf(v.x - mean);
      o.y = f2bf(v.y - mean);
      o.z = f2bf(v.z - mean);
      o.w = f2bf(v.w - mean);
      dst[i] = o;
    }
  }
}

// ---------------------------------------------------------------------------
extern "C" void kernel_launch(void* const* d_in, const int* in_sizes, int n_in,
                              void* d_out, int out_size, void* d_ws,
                              size_t ws_size, hipStream_t stream) {
  const int D = 4096, N = 8192, O = 2048;
  const float* x = (const float*)d_in[0];
  const float* Psi = (const float*)d_in[1];
  float* out = (float*)d_out;

  char* ws = (char*)d_ws;
  unsigned short* xb = (unsigned short*)(ws);                          // 64 MB
  unsigned short* xtb = (unsigned short*)(ws + ((size_t)64 << 20));    // 64 MB
  unsigned short* pc = (unsigned short*)(ws + ((size_t)128 << 20));    // 32 MB
  unsigned short* tmpb = (unsigned short*)(ws + ((size_t)160 << 20));  // 16 MB

  pre_kernel<<<8192 + O, 256, 0, stream>>>(x, Psi, xb, xtb, pc, D, N);
  // GEMM1: tmp[O][D] = pc[O][N] * xb[D][N]^T   (grid 16x16 = 256)
  gemm2p<<<dim3(D / 256, O / 128), 512, 0, stream>>>(pc, xb, tmpb, O, D, N);
  // GEMM2: out[O][N] = tmpb[O][D] * xtb[N][D]^T (grid 32x8 = 256)
  gemm4p<<<dim3(N / 256, O / 256), 512, 0, stream>>>(tmpb, xtb, out, O, N, D);
}

// Round 5
// 537.854 us; speedup vs baseline: 1.0424x; 1.0424x over previous
//
#include <hip/hip_runtime.h>
#include <cstdint>
#include <cstddef>

// ---------------------------------------------------------------------------
// SRPLayer: out = Psi_c @ x.T @ x, Psi_c = Psi - rowmean(Psi)
//   x [4096][8192] f32, Psi [2048][8192] f32, out [2048][8192] f32
// GEMM1 (tmp = pc * xb^T): triple-buffer mega-phase — 1 barrier + 32-MFMA
//   cluster per K-tile, 16 ds_read_b128/wave/tile (minimal), stage kt+2,
//   vmcnt(6) steady. LDS 144KB.
// GEMM2 (out = tmp * xtb^T): round-3 proven 4-phase BM=256 schedule.
// ws: xb [D][N] bf16 @0 | xtb [N][D] bf16 @64MB | pc [O][N] bf16 @128MB
//     | tmpb [O][D] bf16 @160MB
// ---------------------------------------------------------------------------

typedef __bf16 bf16x8 __attribute__((ext_vector_type(8)));
typedef float f32x4 __attribute__((ext_vector_type(4)));

__device__ __forceinline__ unsigned short f2bf(float f) {
  unsigned u = __builtin_bit_cast(unsigned, f);
  u += 0x7FFFu + ((u >> 16) & 1u);
  return (unsigned short)(u >> 16);
}

__device__ __forceinline__ void gload_lds16(const void* g, void* l) {
  // async global->LDS, 16B/lane; LDS dest must be wave-uniform base + lane*16
  __builtin_amdgcn_global_load_lds(
      (const __attribute__((address_space(1))) unsigned int*)g,
      (__attribute__((address_space(3))) unsigned int*)l, 16, 0, 0);
}

__device__ __forceinline__ void barrier_nofence() {
  asm volatile("" ::: "memory");
  __builtin_amdgcn_s_barrier();
  asm volatile("" ::: "memory");
}
#define WAIT_LGKM0()                                   \
  do {                                                 \
    asm volatile("s_waitcnt lgkmcnt(0)" ::: "memory"); \
    __builtin_amdgcn_sched_barrier(0);                 \
  } while (0)
#define WAITV(N) asm volatile("s_waitcnt vmcnt(" #N ")" ::: "memory")

// =============== GEMM1: C[M][Nc] = A[M][K] * B[Nc][K]^T (bf16 out) ==========
// BM=128, BN=256, BK=64. 8 waves 2Mx4N (wave tile 64x64). Triple-buffered
// 48KB tiles; per K-tile: read ALL frags once (16 ds_read_b128), stage all
// 6 gloads for kt+2, one 32-MFMA cluster, WAITV(6), one barrier.
__global__ __launch_bounds__(512, 2) void gemm_tb(
    const unsigned short* __restrict__ A, const unsigned short* __restrict__ B,
    unsigned short* __restrict__ C, int M, int Nc, int K) {
  constexpr int TILE = 49152;     // A 16KB + B 32KB
  constexpr int APLANE = 8192;    // 128 rows x 64B per kk-plane
  constexpr int BPLANE = 16384;   // 256 rows x 64B
  __shared__ __align__(1024) char lds[3 * TILE];  // 144 KB

  const int nwg = gridDim.x * gridDim.y;
  const int wgid = blockIdx.y * gridDim.x + blockIdx.x;
  const int swz = (wgid & 7) * (nwg >> 3) + (wgid >> 3);  // nwg % 8 == 0
  const int bx = swz % gridDim.x, by = swz / gridDim.x;
  const int tileM = by * 128, tileN = bx * 256;

  const int t = threadIdx.x, lane = t & 63, wave = t >> 6;
  const int wm = wave >> 2, wn = wave & 3;
  const int rsel = lane & 15;
  const int cs = (((lane >> 4) ^ (((lane >> 3) & 1) << 1)) << 4);

  const unsigned short* Ag = A + (size_t)tileM * K;
  const unsigned short* Bg = B + (size_t)tileN * K;
  const int cgA = (((t & 3) ^ (((t >> 5) & 1) << 1))) * 8;
  const int NT = K / 64;

  auto stage_tile = [&](int kt) {  // 6 gloads -> buffer kt%3
    char* base = lds + (kt % 3) * TILE;
    // B: 2 halves x 2 kk-planes (4 loads)
#pragma unroll
    for (int h = 0; h < 2; ++h)
#pragma unroll
      for (int kk = 0; kk < 2; ++kk) {
        int r = h * 128 + (t >> 2);
        gload_lds16(Bg + (size_t)r * K + kt * 64 + kk * 32 + cgA,
                    base + 16384 + kk * BPLANE + h * 8192 + t * 16);
      }
    // A: 2 halves, each 1 load covering both kk planes (kk = t>>8)
#pragma unroll
    for (int h = 0; h < 2; ++h) {
      int r = h * 64 + ((t >> 2) & 63);
      int kk = t >> 8;
      gload_lds16(Ag + (size_t)r * K + kt * 64 + kk * 32 + cgA,
                  base + kk * APLANE + h * 4096 + (t & 255) * 16);
    }
  };

  f32x4 acc[4][4] = {};
  bf16x8 aF[4][2], bF[4][2];

  // prologue: tiles 0 and 1 staged; drain tile0 (leave tile1's 6 in flight)
  stage_tile(0);
  stage_tile(1);
  WAITV(6);
  barrier_nofence();

  for (int kt = 0; kt < NT; ++kt) {
    const char* Ab = lds + (kt % 3) * TILE;
    const char* Bb = Ab + 16384;
    // read ALL fragments for this tile (compiler inserts fine lgkmcnt)
#pragma unroll
    for (int f = 0; f < 4; ++f)
#pragma unroll
      for (int kk = 0; kk < 2; ++kk)
        aF[f][kk] = *(const bf16x8*)(Ab + kk * APLANE +
                                     ((2 * f + wm) * 16 + rsel) * 64 + cs);
#pragma unroll
    for (int g = 0; g < 4; ++g)
#pragma unroll
      for (int kk = 0; kk < 2; ++kk)
        bF[g][kk] = *(const bf16x8*)(Bb + kk * BPLANE +
                                     ((4 * g + wn) * 16 + rsel) * 64 + cs);
    if (kt + 2 < NT) stage_tile(kt + 2);
    __builtin_amdgcn_s_setprio(1);
#pragma unroll
    for (int f = 0; f < 4; ++f)
#pragma unroll
      for (int g = 0; g < 4; ++g)
#pragma unroll
        for (int kk = 0; kk < 2; ++kk)
          acc[f][g] = __builtin_amdgcn_mfma_f32_16x16x32_bf16(
              aF[f][kk], bF[g][kk], acc[f][g], 0, 0, 0);
    __builtin_amdgcn_s_setprio(0);
    if (kt + 2 < NT) { WAITV(6); } else { WAITV(0); }
    barrier_nofence();
  }

  // C/D layout: row=(lane>>4)*4+r, col=lane&15 (m89/m91-verified)
#pragma unroll
  for (int f = 0; f < 4; ++f) {
    int row0 = tileM + (2 * f + wm) * 16 + ((lane >> 4) << 2);
#pragma unroll
    for (int g = 0; g < 4; ++g) {
      int col = tileN + (4 * g + wn) * 16 + rsel;
#pragma unroll
      for (int r = 0; r < 4; ++r)
        C[(size_t)(row0 + r) * Nc + col] = f2bf(acc[f][g][r]);
    }
  }
}

// =============== GEMM2: round-3 proven 4-phase BM=BN=256 schedule ===========
__global__ __launch_bounds__(512, 2) void gemm8p256(
    const unsigned short* __restrict__ A, const unsigned short* __restrict__ B,
    float* __restrict__ C, int M, int Nc, int K) {
  constexpr int APLANE = 256 * 64, ABUF = 2 * APLANE;
  constexpr int BPLANE = 256 * 64, BBUF = 2 * BPLANE;
  __shared__ __align__(1024) char lds[2 * ABUF + 2 * BBUF];  // 128 KB
  char* Al = lds;
  char* Bl = lds + 2 * ABUF;

  const int nwg = gridDim.x * gridDim.y;
  const int wgid = blockIdx.y * gridDim.x + blockIdx.x;
  const int swz = (wgid & 7) * (nwg >> 3) + (wgid >> 3);
  const int bx = swz % gridDim.x, by = swz / gridDim.x;
  const int tileM = by * 256, tileN = bx * 256;

  const int t = threadIdx.x, lane = t & 63, wave = t >> 6;
  const int wm = wave >> 2, wn = wave & 3;
  const int rsel = lane & 15;
  const int cs = (((lane >> 4) ^ (((lane >> 3) & 1) << 1)) << 4);

  const unsigned short* Ag = A + (size_t)tileM * K;
  const unsigned short* Bg = B + (size_t)tileN * K;
  const int cgA = (((t & 3) ^ (((t >> 5) & 1) << 1))) * 8;
  const int NT = K / 64;

  auto stageA = [&](int h, int kt) {
    int b2 = kt & 1;
#pragma unroll
    for (int kk = 0; kk < 2; ++kk) {
      int r = h * 128 + (t >> 2);
      gload_lds16(Ag + (size_t)r * K + kt * 64 + kk * 32 + cgA,
                  Al + b2 * ABUF + kk * APLANE + h * 8192 + t * 16);
    }
  };
  auto stageB = [&](int h, int kt) {
    int b2 = kt & 1;
#pragma unroll
    for (int kk = 0; kk < 2; ++kk) {
      int r = h * 128 + (t >> 2);
      gload_lds16(Bg + (size_t)r * K + kt * 64 + kk * 32 + cgA,
                  Bl + b2 * BBUF + kk * BPLANE + h * 8192 + t * 16);
    }
  };

  f32x4 acc[8][4] = {};
  bf16x8 aF[4][2], bF[2][2];

  stageA(0, 0); stageB(1, 0); stageA(1, 0); stageB(0, 0);
  stageA(0, 1); stageB(1, 1); stageA(1, 1);
  WAITV(6);
  barrier_nofence();

  for (int kt = 0; kt < NT; ++kt) {
    const char* Ab = Al + (kt & 1) * ABUF;
    const char* Bb = Bl + (kt & 1) * BBUF;
    // p0: A-mh0 + B-nh0; stage (kt+1).B0; quad (0,0)
#pragma unroll
    for (int f = 0; f < 4; ++f)
#pragma unroll
      for (int kk = 0; kk < 2; ++kk)
        aF[f][kk] = *(const bf16x8*)(Ab + kk * APLANE +
                                     ((2 * f + wm) * 16 + rsel) * 64 + cs);
#pragma unroll
    for (int g = 0; g < 2; ++g)
#pragma unroll
      for (int kk = 0; kk < 2; ++kk)
        bF[g][kk] = *(const bf16x8*)(Bb + kk * BPLANE +
                                     ((4 * g + wn) * 16 + rsel) * 64 + cs);
    if (kt + 1 < NT) stageB(0, kt + 1);
    barrier_nofence();
    WAIT_LGKM0();
    __builtin_amdgcn_s_setprio(1);
#pragma unroll
    for (int f = 0; f < 4; ++f)
#pragma unroll
      for (int g = 0; g < 2; ++g)
#pragma unroll
        for (int kk = 0; kk < 2; ++kk)
          acc[f][g] = __builtin_amdgcn_mfma_f32_16x16x32_bf16(
              aF[f][kk], bF[g][kk], acc[f][g], 0, 0, 0);
    __builtin_amdgcn_s_setprio(0);
    barrier_nofence();
    // p1: B-nh1; stage (kt+2).A0; quad (0,1)
#pragma unroll
    for (int g = 0; g < 2; ++g)
#pragma unroll
      for (int kk = 0; kk < 2; ++kk)
        bF[g][kk] = *(const bf16x8*)(Bb + kk * BPLANE +
                                     ((4 * (g + 2) + wn) * 16 + rsel) * 64 + cs);
    if (kt + 2 < NT) stageA(0, kt + 2);
    barrier_nofence();
    WAIT_LGKM0();
    __builtin_amdgcn_s_setprio(1);
#pragma unroll
    for (int f = 0; f < 4; ++f)
#pragma unroll
      for (int g = 0; g < 2; ++g)
#pragma unroll
        for (int kk = 0; kk < 2; ++kk)
          acc[f][2 + g] = __builtin_amdgcn_mfma_f32_16x16x32_bf16(
              aF[f][kk], bF[g][kk], acc[f][2 + g], 0, 0, 0);
    __builtin_amdgcn_s_setprio(0);
    barrier_nofence();
    // p2: A-mh1; stage (kt+2).B1; quad (1,1)
#pragma unroll
    for (int f = 0; f < 4; ++f)
#pragma unroll
      for (int kk = 0; kk < 2; ++kk)
        aF[f][kk] = *(const bf16x8*)(Ab + kk * APLANE +
                                     ((2 * (f + 4) + wm) * 16 + rsel) * 64 + cs);
    if (kt + 2 < NT) stageB(1, kt + 2);
    barrier_nofence();
    WAIT_LGKM0();
    __builtin_amdgcn_s_setprio(1);
#pragma unroll
    for (int f = 0; f < 4; ++f)
#pragma unroll
      for (int g = 0; g < 2; ++g)
#pragma unroll
        for (int kk = 0; kk < 2; ++kk)
          acc[4 + f][2 + g] = __builtin_amdgcn_mfma_f32_16x16x32_bf16(
              aF[f][kk], bF[g][kk], acc[4 + f][2 + g], 0, 0, 0);
    __builtin_amdgcn_s_setprio(0);
    barrier_nofence();
    // p3: re-read B-nh0; stage (kt+2).A1; quad (1,0)
#pragma unroll
    for (int g = 0; g < 2; ++g)
#pragma unroll
      for (int kk = 0; kk < 2; ++kk)
        bF[g][kk] = *(const bf16x8*)(Bb + kk * BPLANE +
                                     ((4 * g + wn) * 16 + rsel) * 64 + cs);
    if (kt + 2 < NT) stageA(1, kt + 2);
    barrier_nofence();
    WAIT_LGKM0();
    __builtin_amdgcn_s_setprio(1);
#pragma unroll
    for (int f = 0; f < 4; ++f)
#pragma unroll
      for (int g = 0; g < 2; ++g)
#pragma unroll
        for (int kk = 0; kk < 2; ++kk)
          acc[4 + f][g] = __builtin_amdgcn_mfma_f32_16x16x32_bf16(
              aF[f][kk], bF[g][kk], acc[4 + f][g], 0, 0, 0);
    __builtin_amdgcn_s_setprio(0);
    if (kt + 2 < NT) { WAITV(6); } else { WAITV(0); }
    barrier_nofence();
  }

#pragma unroll
  for (int f = 0; f < 8; ++f) {
    int row0 = tileM + (2 * f + wm) * 16 + ((lane >> 4) << 2);
#pragma unroll
    for (int g = 0; g < 4; ++g) {
      int col = tileN + (4 * g + wn) * 16 + rsel;
#pragma unroll
      for (int r = 0; r < 4; ++r)
        C[(size_t)(row0 + r) * Nc + col] = acc[f][g][r];
    }
  }
}

// ====== fused preprocessing: x -> {xb, xtb}; Psi -> centered bf16 pc ========
__global__ void pre_kernel(const float* __restrict__ x,
                           const float* __restrict__ Psi,
                           unsigned short* __restrict__ xb,
                           unsigned short* __restrict__ xtb,
                           unsigned short* __restrict__ pc, int D, int N) {
  __shared__ unsigned short tileT[64][66];
  __shared__ float red[4];
  const int bid = blockIdx.x, t = threadIdx.x;
  if (bid < 8192) {
    const int n0 = (bid & 127) * 64, d0 = (bid >> 7) * 64;
    const int tx = t & 15, ty = t >> 4;  // 16 x 16
#pragma unroll
    for (int dy = 0; dy < 4; ++dy) {
      int d = ty + 16 * dy;
      float4 v = *(const float4*)(x + (size_t)(d0 + d) * N + n0 + tx * 4);
      ushort4 o;
      o.x = f2bf(v.x); o.y = f2bf(v.y); o.z = f2bf(v.z); o.w = f2bf(v.w);
      *(ushort4*)(xb + (size_t)(d0 + d) * N + n0 + tx * 4) = o;
      tileT[tx * 4 + 0][d] = o.x;
      tileT[tx * 4 + 1][d] = o.y;
      tileT[tx * 4 + 2][d] = o.z;
      tileT[tx * 4 + 3][d] = o.w;
    }
    __syncthreads();
#pragma unroll
    for (int ny = 0; ny < 4; ++ny) {
      int n = ty + 16 * ny;
      ushort2 a = *(const ushort2*)&tileT[n][tx * 4];
      ushort2 b = *(const ushort2*)&tileT[n][tx * 4 + 2];
      ushort4 o; o.x = a.x; o.y = a.y; o.z = b.x; o.w = b.y;
      *(ushort4*)(xtb + (size_t)(n0 + n) * D + d0 + tx * 4) = o;
    }
  } else {
    const int row = bid - 8192;
    const float4* src = (const float4*)(Psi + (size_t)row * N);
    int n4 = N >> 2;
    float s = 0.f;
    for (int i = t; i < n4; i += blockDim.x) {
      float4 v = src[i];
      s += (v.x + v.y) + (v.z + v.w);
    }
#pragma unroll
    for (int off = 32; off > 0; off >>= 1) s += __shfl_down(s, off);
    if ((t & 63) == 0) red[t >> 6] = s;
    __syncthreads();
    float mean = (red[0] + red[1] + red[2] + red[3]) / (float)N;
    ushort4* dst = (ushort4*)(pc + (size_t)row * N);
    for (int i = t; i < n4; i += blockDim.x) {
      float4 v = src[i];
      ushort4 o;
      o.x = f2bf(v.x - mean);
      o.y = f2bf(v.y - mean);
      o.z = f2bf(v.z - mean);
      o.w = f2bf(v.w - mean);
      dst[i] = o;
    }
  }
}

// ---------------------------------------------------------------------------
extern "C" void kernel_launch(void* const* d_in, const int* in_sizes, int n_in,
                              void* d_out, int out_size, void* d_ws,
                              size_t ws_size, hipStream_t stream) {
  const int D = 4096, N = 8192, O = 2048;
  const float* x = (const float*)d_in[0];
  const float* Psi = (const float*)d_in[1];
  float* out = (float*)d_out;

  char* ws = (char*)d_ws;
  unsigned short* xb = (unsigned short*)(ws);                          // 64 MB
  unsigned short* xtb = (unsigned short*)(ws + ((size_t)64 << 20));    // 64 MB
  unsigned short* pc = (unsigned short*)(ws + ((size_t)128 << 20));    // 32 MB
  unsigned short* tmpb = (unsigned short*)(ws + ((size_t)160 << 20));  // 16 MB

  pre_kernel<<<8192 + O, 256, 0, stream>>>(x, Psi, xb, xtb, pc, D, N);
  // GEMM1: tmp[O][D] = pc[O][N] * xb[D][N]^T   (grid 16x16 = 256)
  gemm_tb<<<dim3(D / 256, O / 128), 512, 0, stream>>>(pc, xb, tmpb, O, D, N);
  // GEMM2: out[O][N] = tmpb[O][D] * xtb[N][D]^T (grid 32x8 = 256)
  gemm8p256<<<dim3(N / 256, O / 256), 512, 0, stream>>>(tmpb, xtb, out, O, N, D);
}